// Round 8
// baseline (416.196 us; speedup 1.0000x reference)
//
#include <hip/hip_runtime.h>
#include <hip/hip_bf16.h>
#include <stdint.h>

#define DDIM 256
#define NROWS 8192
#define LOG2E5 7.2134752044448170f   // 5 / ln(2): exp(5x) = exp2(LOG2E5 * x)

typedef __attribute__((ext_vector_type(4))) float floatx4;
typedef __attribute__((ext_vector_type(2))) long longx2;

// Fragment-order fp8 layout (for mfma_f32_16x16x32_fp8_fp8, A and B same):
//   R-group Rg = 16 rows (16Rg + m), k-pair kp = 64 k-values.
//   1 KB block at (Rg*4 + kp)*1024; lane slot = lane*16 (lane = q*16 + m);
//   bytes [0:7] = row m, k = kp*64 +  0 + q*8 + j   (ks = 2kp)
//   bytes [8:15]= row m, k = kp*64 + 32 + q*8 + j   (ks = 2kp+1)
// GEMM fragment load = one contiguous 1 KB global_load_dwordx4 per wave.

// Kernel 1: normalize 16 rows per block, fp8-quantize, repack to frag order.
__global__ __launch_bounds__(256) void normalize_repack_fp8(
    const float* __restrict__ U, const float* __restrict__ P,
    unsigned char* __restrict__ Af, unsigned char* __restrict__ Pf,
    float* __restrict__ possim, float* __restrict__ rowsum,
    float* __restrict__ out, int* __restrict__ counter)
{
    __shared__ unsigned char Ut[16 * 272];   // 272 = 256 + 16 pad
    __shared__ unsigned char Pt[16 * 272];
    const int tid = threadIdx.x;
    const int Rg  = blockIdx.x;            // 0..511
    const int r16 = tid >> 4;              // row in group
    const int c   = tid & 15;              // 16 threads/row, 16 elems each
    const int row = Rg * 16 + r16;

    if (Rg == 0 && tid == 0) { out[0] = 0.0f; counter[0] = 0; }
    if (c == 0) rowsum[row] = 0.0f;

    float4 u4[4], p4[4];
    float su = 0.0f, sp = 0.0f, up = 0.0f;
    #pragma unroll
    for (int j = 0; j < 4; ++j) {
        const size_t base = (size_t)row * DDIM + c * 16 + j * 4;
        u4[j] = *(const float4*)(U + base);
        p4[j] = *(const float4*)(P + base);
        su += u4[j].x*u4[j].x + u4[j].y*u4[j].y + u4[j].z*u4[j].z + u4[j].w*u4[j].w;
        sp += p4[j].x*p4[j].x + p4[j].y*p4[j].y + p4[j].z*p4[j].z + p4[j].w*p4[j].w;
        up += u4[j].x*p4[j].x + u4[j].y*p4[j].y + u4[j].z*p4[j].z + u4[j].w*p4[j].w;
    }
    #pragma unroll
    for (int d = 1; d < 16; d <<= 1) {     // row's 16 lanes are contiguous
        su += __shfl_xor(su, d);
        sp += __shfl_xor(sp, d);
        up += __shfl_xor(up, d);
    }
    const float iu = rsqrtf(fmaxf(su, 1e-24f));
    const float ip = rsqrtf(fmaxf(sp, 1e-24f));
    if (c == 0) possim[row] = up * iu * ip;

    int4 qu, qp;
    int* quv = (int*)&qu; int* qpv = (int*)&qp;
    #pragma unroll
    for (int j = 0; j < 4; ++j) {
        int t;
        t = __builtin_amdgcn_cvt_pk_fp8_f32(u4[j].x * iu, u4[j].y * iu, 0, false);
        t = __builtin_amdgcn_cvt_pk_fp8_f32(u4[j].z * iu, u4[j].w * iu, t, true);
        quv[j] = t;
        t = __builtin_amdgcn_cvt_pk_fp8_f32(p4[j].x * ip, p4[j].y * ip, 0, false);
        t = __builtin_amdgcn_cvt_pk_fp8_f32(p4[j].z * ip, p4[j].w * ip, t, true);
        qpv[j] = t;
    }
    *(int4*)&Ut[r16 * 272 + c * 16] = qu;
    *(int4*)&Pt[r16 * 272 + c * 16] = qp;
    __syncthreads();

    // Repack: wave wv handles k-pair kp = wv; lane (m = lane&15, q = lane>>4)
    // gathers its two 8B granules and stores one 16B slot; wave store = 1 KB.
    const int lane = tid & 63;
    const int kp   = tid >> 6;
    const int m = lane & 15, q = lane >> 4;
    const int lb = m * 272 + kp * 64 + q * 8;
    int4 vu, vp;
    *(int2*)&vu.x = *(const int2*)&Ut[lb];
    *(int2*)&vu.z = *(const int2*)&Ut[lb + 32];
    *(int2*)&vp.x = *(const int2*)&Pt[lb];
    *(int2*)&vp.z = *(const int2*)&Pt[lb + 32];
    const size_t o = (size_t)(Rg * 4 + kp) * 1024 + lane * 16;
    *(int4*)(Af + o) = vu;
    *(int4*)(Pf + o) = vp;
}

// Kernel 2: fp8 GEMM + exp-rowsum + fused finalize. NO LDS, NO barriers in
// the K-loop. 4096 blocks x 4 independent waves; each wave owns a 64x64
// output tile (4x4 mfma_f32_16x16x32_fp8_fp8, acc = 64 VGPR). Per k-pair:
// 8 contiguous 1 KB fragment loads (prefetched depth-1) + 32 MFMAs.
// XCD band swizzle (blockIdx&7): per-XCD set = A 2 MB + B band 256 KB < L2.
__global__ __launch_bounds__(256) void sim_exp_rowsum(
    const unsigned char* __restrict__ Af,
    const unsigned char* __restrict__ Pf,
    float* __restrict__ rowsum,
    const float* __restrict__ possim,
    int* __restrict__ counter,
    float* __restrict__ out)
{
    __shared__ float ws4[4];
    __shared__ int ticket_s;
    const int tid  = threadIdx.x;
    const int lane = tid & 63;
    const int wv   = tid >> 6;
    const int wr   = wv >> 1, wc = wv & 1;
    const int m = lane & 15, q = lane >> 4;

    const int oct = blockIdx.x & 7;
    const int lin = blockIdx.x >> 3;       // 0..511
    const int CX  = oct * 8 + (lin & 7);   // col 128-tile, XCD-local band
    const int RY  = lin >> 3;              // row 128-tile

    // wave fragment bases; t/u stride = 4 KB, kp stride = 1 KB
    const unsigned char* Ab = Af + (size_t)(RY * 8 + wr * 4) * 4096 + lane * 16;
    const unsigned char* Bb = Pf + (size_t)(CX * 8 + wc * 4) * 4096 + lane * 16;

    floatx4 acc[4][4];
    #pragma unroll
    for (int t = 0; t < 4; ++t)
        #pragma unroll
        for (int u = 0; u < 4; ++u)
            acc[t][u] = {0.0f, 0.0f, 0.0f, 0.0f};

    longx2 a[4], b[4];
    #pragma unroll
    for (int t = 0; t < 4; ++t) a[t] = *(const longx2*)(Ab + t * 4096);
    #pragma unroll
    for (int u = 0; u < 4; ++u) b[u] = *(const longx2*)(Bb + u * 4096);

    #pragma unroll
    for (int kp = 0; kp < 4; ++kp) {
        longx2 an[4], bn[4];
        if (kp < 3) {
            #pragma unroll
            for (int t = 0; t < 4; ++t)
                an[t] = *(const longx2*)(Ab + t * 4096 + (kp + 1) * 1024);
            #pragma unroll
            for (int u = 0; u < 4; ++u)
                bn[u] = *(const longx2*)(Bb + u * 4096 + (kp + 1) * 1024);
        }
        #pragma unroll
        for (int t = 0; t < 4; ++t)
            #pragma unroll
            for (int u = 0; u < 4; ++u)
                acc[t][u] = __builtin_amdgcn_mfma_f32_16x16x32_fp8_fp8(
                    a[t].x, b[u].x, acc[t][u], 0, 0, 0);
        #pragma unroll
        for (int t = 0; t < 4; ++t)
            #pragma unroll
            for (int u = 0; u < 4; ++u)
                acc[t][u] = __builtin_amdgcn_mfma_f32_16x16x32_fp8_fp8(
                    a[t].y, b[u].y, acc[t][u], 0, 0, 0);
        if (kp < 3) {
            #pragma unroll
            for (int t = 0; t < 4; ++t) { a[t] = an[t]; b[t] = bn[t]; }
        }
    }

    // Epilogue: C/D col = m, row = q*4 + r (+t*16). exp2 all 64 values,
    // sum 4 u-tiles in-lane, xor-reduce 16 col-lanes, atomic per row.
    #pragma unroll
    for (int t = 0; t < 4; ++t) {
        #pragma unroll
        for (int r = 0; r < 4; ++r) {
            float s = exp2f(LOG2E5 * acc[t][0][r]) + exp2f(LOG2E5 * acc[t][1][r])
                    + exp2f(LOG2E5 * acc[t][2][r]) + exp2f(LOG2E5 * acc[t][3][r]);
            s += __shfl_xor(s, 1);
            s += __shfl_xor(s, 2);
            s += __shfl_xor(s, 4);
            s += __shfl_xor(s, 8);
            if (m == 0) {
                const int grow = RY * 128 + wr * 64 + t * 16 + q * 4 + r;
                atomicAdd(&rowsum[grow], s);
            }
        }
    }

    // Fused finalize: last block computes loss = mean(log(rowsum) - 5*possim).
    __threadfence();
    __syncthreads();
    if (tid == 0)
        ticket_s = __hip_atomic_fetch_add(counter, 1, __ATOMIC_ACQ_REL,
                                          __HIP_MEMORY_SCOPE_AGENT);
    __syncthreads();
    if (ticket_s == 4095) {
        float part = 0.0f;
        for (int idx = tid; idx < NROWS; idx += 256) {
            const float rs = __hip_atomic_load(&rowsum[idx], __ATOMIC_RELAXED,
                                               __HIP_MEMORY_SCOPE_AGENT);
            part += __logf(rs) - 5.0f * possim[idx];
        }
        #pragma unroll
        for (int d = 1; d < 64; d <<= 1) part += __shfl_xor(part, d);
        if (lane == 0) ws4[wv] = part;
        __syncthreads();
        if (tid == 0)
            out[0] = (ws4[0] + ws4[1] + ws4[2] + ws4[3]) * (1.0f / (float)NROWS);
    }
}

extern "C" void kernel_launch(void* const* d_in, const int* in_sizes, int n_in,
                              void* d_out, int out_size, void* d_ws, size_t ws_size,
                              hipStream_t stream) {
    const float* U = (const float*)d_in[0];
    const float* P = (const float*)d_in[1];
    float* out = (float*)d_out;
    char* ws = (char*)d_ws;
    // ws: Af fp8 frag-order (2 MB) | Pf (2 MB) | rowsum (32 KB) | possim (32 KB) | counter
    unsigned char* Af = (unsigned char*)ws;
    unsigned char* Pf = (unsigned char*)(ws + 2097152);
    float* rowsum = (float*)(ws + 4194304);
    float* possim = (float*)(ws + 4194304 + 32768);
    int* counter  = (int*)(ws + 4194304 + 65536);

    normalize_repack_fp8<<<NROWS / 16, 256, 0, stream>>>(U, P, Af, Pf, possim,
                                                         rowsum, out, counter);
    sim_exp_rowsum<<<4096, 256, 0, stream>>>(Af, Pf, rowsum, possim, counter, out);
}